// Round 1
// baseline (2660.089 us; speedup 1.0000x reference)
//
#include <hip/hip_runtime.h>
#include <math.h>

#define NN 20000
#define NE 320000
#define TS 16
#define HG 64
#define HTT 128
#define NG 384   // 3*HT
#define LN_EPS 1e-5f

__device__ __forceinline__ float wave_sum64(float v) {
  #pragma unroll
  for (int off = 32; off > 0; off >>= 1) v += __shfl_xor(v, off, 64);
  return v;
}

// ---------------- setup: degree + CSR ----------------
__global__ void k_init(int* cnt, float* h) {
  int i = blockIdx.x * blockDim.x + threadIdx.x;
  int stride = gridDim.x * blockDim.x;
  for (int j = i; j < NN; j += stride) cnt[j] = 0;
  for (int j = i; j < NN * HTT; j += stride) h[j] = 0.f;
}

__global__ void k_hist(const int* __restrict__ dst, int* cnt) {
  int e = blockIdx.x * blockDim.x + threadIdx.x;
  if (e < NE) atomicAdd(&cnt[dst[e]], 1);
}

// single block, 1024 threads: exclusive scan of counts -> row_ptr, cursor, deg_inv
__global__ void k_scan(int* cnt /*in counts, out cursor*/, int* row_ptr, float* deg_inv) {
  __shared__ int s[1024];
  int tid = threadIdx.x;
  int carry = 0;
  for (int base = 0; base < NN; base += 1024) {
    int n = base + tid;
    int v = (n < NN) ? cnt[n] : 0;
    s[tid] = v;
    __syncthreads();
    for (int off = 1; off < 1024; off <<= 1) {
      int t = (tid >= off) ? s[tid - off] : 0;
      __syncthreads();
      s[tid] += t;
      __syncthreads();
    }
    int incl = s[tid];
    if (n < NN) {
      int excl = carry + incl - v;
      row_ptr[n] = excl;
      cnt[n] = excl;                      // cursor starts at row begin
      deg_inv[n] = 1.0f / (float)((v > 1) ? v : 1);
    }
    carry += s[1023];
    __syncthreads();
  }
  if (tid == 0) row_ptr[NN] = carry;
}

__global__ void k_fill(const int* __restrict__ src, const int* __restrict__ dst,
                       int* cursor, int* col) {
  int e = blockIdx.x * blockDim.x + threadIdx.x;
  if (e < NE) {
    int p = atomicAdd(&cursor[dst[e]], 1);
    col[p] = src[e];
  }
}

// ---------------- SAGE layer 0 (F=1 -> HG), one wave per node ----------------
__global__ __launch_bounds__(256) void k_sage0(
    const float* __restrict__ x_t,
    const int* __restrict__ row_ptr, const int* __restrict__ col,
    const float* __restrict__ deg_inv,
    const float* __restrict__ Wl0, const float* __restrict__ Wr0,
    const float* __restrict__ b0,
    const float* __restrict__ g0, const float* __restrict__ be0,
    float* __restrict__ h0) {
  int lane = threadIdx.x & 63;
  int n = blockIdx.x * 4 + (threadIdx.x >> 6);
  if (n >= NN) return;
  int beg = row_ptr[n], end = row_ptr[n + 1];
  float s = 0.f;
  for (int e = beg + lane; e < end; e += 64) s += x_t[col[e]];
  float a = wave_sum64(s) * deg_inv[n];
  float xn = x_t[n];
  float v = a * Wl0[lane] + xn * Wr0[lane] + b0[lane];
  float mu = wave_sum64(v) * (1.f / 64.f);
  float d = v - mu;
  float var = wave_sum64(d * d) * (1.f / 64.f);
  float o = d * rsqrtf(var + LN_EPS) * g0[lane] + be0[lane];
  h0[n * HG + lane] = fmaxf(o, 0.f);
}

// ---------------- SAGE layer 1 (HG -> HG), one wave per node ----------------
__global__ __launch_bounds__(256) void k_sage1(
    const float* __restrict__ h0,
    const int* __restrict__ row_ptr, const int* __restrict__ col,
    const float* __restrict__ deg_inv,
    const float* __restrict__ Wl1, const float* __restrict__ Wr1,
    const float* __restrict__ b1,
    const float* __restrict__ g1, const float* __restrict__ be1,
    float* __restrict__ Ht) {
  __shared__ float Wl[HG * HG];
  __shared__ float Wr[HG * HG];
  for (int i = threadIdx.x * 4; i < HG * HG; i += 1024) {
    *(float4*)&Wl[i] = *(const float4*)&Wl1[i];
    *(float4*)&Wr[i] = *(const float4*)&Wr1[i];
  }
  __syncthreads();
  int lane = threadIdx.x & 63;
  int n = blockIdx.x * 4 + (threadIdx.x >> 6);
  if (n >= NN) return;  // NN % 4 == 0, no barrier after this point
  int beg = row_ptr[n], end = row_ptr[n + 1];
  float aggv = 0.f;
  for (int e = beg; e < end; e++) {
    int c = col[e];                       // wave-uniform; broadcast load
    aggv += h0[c * HG + lane];            // coalesced 256B per edge
  }
  aggv *= deg_inv[n];
  float hv = h0[n * HG + lane];
  float acc = b1[lane];
  #pragma unroll 8
  for (int k = 0; k < HG; k++) {
    float ak = __shfl(aggv, k, 64);
    float hk = __shfl(hv, k, 64);
    acc += ak * Wl[k * HG + lane] + hk * Wr[k * HG + lane];
  }
  float mu = wave_sum64(acc) * (1.f / 64.f);
  float d = acc - mu;
  float var = wave_sum64(d * d) * (1.f / 64.f);
  float o = d * rsqrtf(var + LN_EPS) * g1[lane] + be1[lane];
  Ht[n * HG + lane] = fmaxf(o, 0.f);
}

// ---------------- fp32 GEMM: C[m][g] = bias[g] + sum_k A[m][k] * W[g][k] ----------------
// 256 threads, 64x64 tile, 4x4 microtile, K chunks of 16.
__global__ __launch_bounds__(256) void k_gemm_bias(
    const float* __restrict__ A, const float* __restrict__ W,
    const float* __restrict__ bias, float* __restrict__ C, int M, int K) {
  __shared__ float As[16][68];
  __shared__ float Bs[16][68];
  int tid = threadIdx.x;
  int bm = blockIdx.x * 64, bg = blockIdx.y * 64;
  int tx = tid & 15, ty = tid >> 4;
  int lr = tid >> 2, lc = (tid & 3) * 4;
  float acc[4][4] = {{0.f}};
  for (int kk = 0; kk < K; kk += 16) {
    float4 av = make_float4(0.f, 0.f, 0.f, 0.f);
    int gr = bm + lr;
    if (gr < M) av = *(const float4*)&A[gr * K + kk + lc];
    As[lc + 0][lr] = av.x; As[lc + 1][lr] = av.y;
    As[lc + 2][lr] = av.z; As[lc + 3][lr] = av.w;
    float4 bv = *(const float4*)&W[(bg + lr) * K + kk + lc];
    Bs[lc + 0][lr] = bv.x; Bs[lc + 1][lr] = bv.y;
    Bs[lc + 2][lr] = bv.z; Bs[lc + 3][lr] = bv.w;
    __syncthreads();
    #pragma unroll
    for (int k = 0; k < 16; k++) {
      float4 a = *(const float4*)&As[k][ty * 4];
      float4 b = *(const float4*)&Bs[k][tx * 4];
      acc[0][0] += a.x * b.x; acc[0][1] += a.x * b.y; acc[0][2] += a.x * b.z; acc[0][3] += a.x * b.w;
      acc[1][0] += a.y * b.x; acc[1][1] += a.y * b.y; acc[1][2] += a.y * b.z; acc[1][3] += a.y * b.w;
      acc[2][0] += a.z * b.x; acc[2][1] += a.z * b.y; acc[2][2] += a.z * b.z; acc[2][3] += a.z * b.w;
      acc[3][0] += a.w * b.x; acc[3][1] += a.w * b.y; acc[3][2] += a.w * b.z; acc[3][3] += a.w * b.w;
    }
    __syncthreads();
  }
  #pragma unroll
  for (int i = 0; i < 4; i++) {
    int m = bm + ty * 4 + i;
    if (m < M) {
      int g = bg + tx * 4;
      float4 o;
      o.x = acc[i][0] + bias[g + 0];
      o.y = acc[i][1] + bias[g + 1];
      o.z = acc[i][2] + bias[g + 2];
      o.w = acc[i][3] + bias[g + 3];
      *(float4*)&C[m * NG + g] = o;
    }
  }
}

// ---------------- GRU elementwise update ----------------
__global__ void k_gru_update(const float* __restrict__ gi, const float* __restrict__ gh,
                             float* __restrict__ h) {
  int idx = blockIdx.x * blockDim.x + threadIdx.x;
  if (idx >= NN * HTT) return;
  int n = idx >> 7, j = idx & 127;
  const float* gin = gi + n * NG;
  const float* ghn = gh + n * NG;
  float r = 1.f / (1.f + expf(-(gin[j] + ghn[j])));
  float z = 1.f / (1.f + expf(-(gin[HTT + j] + ghn[HTT + j])));
  float nn = tanhf(gin[2 * HTT + j] + r * ghn[2 * HTT + j]);
  h[idx] = (1.f - z) * nn + z * h[idx];
}

// ---------------- head ----------------
__global__ __launch_bounds__(256) void k_head(
    const float* __restrict__ h, const float* __restrict__ hw,
    const float* __restrict__ hb, float* __restrict__ out) {
  int lane = threadIdx.x & 63;
  int n = blockIdx.x * 4 + (threadIdx.x >> 6);
  if (n >= NN) return;
  float v = h[n * HTT + lane] * hw[lane] + h[n * HTT + 64 + lane] * hw[64 + lane];
  v = wave_sum64(v);
  if (lane == 0) out[n] = v + hb[0];
}

extern "C" void kernel_launch(void* const* d_in, const int* in_sizes, int n_in,
                              void* d_out, int out_size, void* d_ws, size_t ws_size,
                              hipStream_t stream) {
  const float* x_seq = (const float*)d_in[0];     // (1,T,N,1)
  const int*   edge  = (const int*)d_in[1];       // (2,E)
  const float* Wl0   = (const float*)d_in[2];
  const float* Wr0   = (const float*)d_in[3];
  const float* b0    = (const float*)d_in[4];
  const float* g0    = (const float*)d_in[5];
  const float* be0   = (const float*)d_in[6];
  const float* Wl1   = (const float*)d_in[7];
  const float* Wr1   = (const float*)d_in[8];
  const float* b1    = (const float*)d_in[9];
  const float* g1    = (const float*)d_in[10];
  const float* be1   = (const float*)d_in[11];
  const float* Wih   = (const float*)d_in[12];    // (384,64)
  const float* Whh   = (const float*)d_in[13];    // (384,128)
  const float* bih   = (const float*)d_in[14];
  const float* bhh   = (const float*)d_in[15];
  const float* headW = (const float*)d_in[16];
  const float* headb = (const float*)d_in[17];
  float* out = (float*)d_out;

  const int* srcp = edge;
  const int* dstp = edge + NE;

  char* ws = (char*)d_ws;
  size_t off = 0;
  auto alloc = [&](size_t bytes) -> void* {
    void* p = ws + off;
    off += (bytes + 255) & ~(size_t)255;
    return p;
  };
  int*   cnt     = (int*)alloc(NN * 4);           // counts, then cursor
  int*   row_ptr = (int*)alloc((NN + 1) * 4);
  int*   col     = (int*)alloc(NE * 4);
  float* deg_inv = (float*)alloc(NN * 4);
  float* h0      = (float*)alloc((size_t)NN * HG * 4);
  float* Ht      = (float*)alloc((size_t)NN * HG * 4);
  float* h       = (float*)alloc((size_t)NN * HTT * 4);
  float* gi      = (float*)alloc((size_t)NN * NG * 4);
  float* gh      = (float*)alloc((size_t)NN * NG * 4);
  (void)ws_size; (void)in_sizes; (void)n_in; (void)out_size;

  k_init<<<512, 256, 0, stream>>>(cnt, h);
  k_hist<<<(NE + 255) / 256, 256, 0, stream>>>(dstp, cnt);
  k_scan<<<1, 1024, 0, stream>>>(cnt, row_ptr, deg_inv);
  k_fill<<<(NE + 255) / 256, 256, 0, stream>>>(srcp, dstp, cnt, col);

  dim3 gemmGrid((NN + 63) / 64, NG / 64);
  for (int t = 0; t < TS; t++) {
    const float* x_t = x_seq + (size_t)t * NN;
    k_sage0<<<5000, 256, 0, stream>>>(x_t, row_ptr, col, deg_inv,
                                      Wl0, Wr0, b0, g0, be0, h0);
    k_sage1<<<5000, 256, 0, stream>>>(h0, row_ptr, col, deg_inv,
                                      Wl1, Wr1, b1, g1, be1, Ht);
    k_gemm_bias<<<gemmGrid, 256, 0, stream>>>(Ht, Wih, bih, gi, NN, HG);
    k_gemm_bias<<<gemmGrid, 256, 0, stream>>>(h, Whh, bhh, gh, NN, HTT);
    k_gru_update<<<(NN * HTT + 255) / 256, 256, 0, stream>>>(gi, gh, h);
  }
  k_head<<<5000, 256, 0, stream>>>(h, headW, headb, out);
}

// Round 2
// 1999.275 us; speedup vs baseline: 1.3305x; 1.3305x over previous
//
#include <hip/hip_runtime.h>
#include <math.h>

#define NN 20000
#define NE 320000
#define TS 16
#define HG 64
#define HTT 128
#define NG 384   // 3*HT
#define LN_EPS 1e-5f

typedef __attribute__((ext_vector_type(8))) short bf16x8;
typedef __attribute__((ext_vector_type(4))) float f32x4;

__device__ __forceinline__ float wave_sum64(float v) {
  #pragma unroll
  for (int off = 32; off > 0; off >>= 1) v += __shfl_xor(v, off, 64);
  return v;
}

__device__ __forceinline__ unsigned short f2bf(float x) {
  unsigned u = __float_as_uint(x);
  unsigned r = u + 0x7FFFu + ((u >> 16) & 1u);   // round-nearest-even to bf16
  return (unsigned short)(r >> 16);
}
__device__ __forceinline__ float bf2f(unsigned short h) {
  return __uint_as_float(((unsigned)h) << 16);
}

// ---------------- setup ----------------
__global__ void k_init(int* cnt, float* h, unsigned short* h_hi, unsigned short* h_lo) {
  int i = blockIdx.x * blockDim.x + threadIdx.x;
  int stride = gridDim.x * blockDim.x;
  for (int j = i; j < NN; j += stride) cnt[j] = 0;
  for (int j = i; j < NN * HTT; j += stride) {
    h[j] = 0.f; h_hi[j] = 0; h_lo[j] = 0;
  }
}

__global__ void k_hist(const int* __restrict__ dst, int* cnt) {
  int e = blockIdx.x * blockDim.x + threadIdx.x;
  if (e < NE) atomicAdd(&cnt[dst[e]], 1);
}

__global__ void k_scan(int* cnt, int* row_ptr, float* deg_inv) {
  __shared__ int s[1024];
  int tid = threadIdx.x;
  int carry = 0;
  for (int base = 0; base < NN; base += 1024) {
    int n = base + tid;
    int v = (n < NN) ? cnt[n] : 0;
    s[tid] = v;
    __syncthreads();
    for (int off = 1; off < 1024; off <<= 1) {
      int t = (tid >= off) ? s[tid - off] : 0;
      __syncthreads();
      s[tid] += t;
      __syncthreads();
    }
    int incl = s[tid];
    if (n < NN) {
      int excl = carry + incl - v;
      row_ptr[n] = excl;
      cnt[n] = excl;
      deg_inv[n] = 1.0f / (float)((v > 1) ? v : 1);
    }
    carry += s[1023];
    __syncthreads();
  }
  if (tid == 0) row_ptr[NN] = carry;
}

__global__ void k_fill(const int* __restrict__ src, const int* __restrict__ dst,
                       int* cursor, int* col) {
  int e = blockIdx.x * blockDim.x + threadIdx.x;
  if (e < NE) {
    int p = atomicAdd(&cursor[dst[e]], 1);
    col[p] = src[e];
  }
}

// convert fp32 weights to split-bf16 planes
__global__ void k_cvt(const float* __restrict__ w, unsigned short* __restrict__ hi,
                      unsigned short* __restrict__ lo, int n) {
  int i = blockIdx.x * blockDim.x + threadIdx.x;
  if (i < n) {
    float x = w[i];
    unsigned short h = f2bf(x);
    hi[i] = h;
    lo[i] = f2bf(x - bf2f(h));
  }
}

// ---------------- SAGE layer 0 (F=1 -> HG) ----------------
__global__ __launch_bounds__(256) void k_sage0(
    const float* __restrict__ x_t,
    const int* __restrict__ row_ptr, const int* __restrict__ col,
    const float* __restrict__ deg_inv,
    const float* __restrict__ Wl0, const float* __restrict__ Wr0,
    const float* __restrict__ b0,
    const float* __restrict__ g0, const float* __restrict__ be0,
    float* __restrict__ h0) {
  int lane = threadIdx.x & 63;
  int n = blockIdx.x * 4 + (threadIdx.x >> 6);
  if (n >= NN) return;
  int beg = row_ptr[n], end = row_ptr[n + 1];
  float s = 0.f;
  for (int e = beg + lane; e < end; e += 64) s += x_t[col[e]];
  float a = wave_sum64(s) * deg_inv[n];
  float xn = x_t[n];
  float v = a * Wl0[lane] + xn * Wr0[lane] + b0[lane];
  float mu = wave_sum64(v) * (1.f / 64.f);
  float d = v - mu;
  float var = wave_sum64(d * d) * (1.f / 64.f);
  float o = d * rsqrtf(var + LN_EPS) * g0[lane] + be0[lane];
  h0[n * HG + lane] = fmaxf(o, 0.f);
}

// ---------------- SAGE layer 1 (HG -> HG), ILP-unrolled gather ----------------
__global__ __launch_bounds__(256) void k_sage1(
    const float* __restrict__ h0,
    const int* __restrict__ row_ptr, const int* __restrict__ col,
    const float* __restrict__ deg_inv,
    const float* __restrict__ Wl1, const float* __restrict__ Wr1,
    const float* __restrict__ b1,
    const float* __restrict__ g1, const float* __restrict__ be1,
    unsigned short* __restrict__ Ht_hi, unsigned short* __restrict__ Ht_lo) {
  __shared__ float Wl[HG * HG];
  __shared__ float Wr[HG * HG];
  for (int i = threadIdx.x * 4; i < HG * HG; i += 1024) {
    *(float4*)&Wl[i] = *(const float4*)&Wl1[i];
    *(float4*)&Wr[i] = *(const float4*)&Wr1[i];
  }
  __syncthreads();
  int lane = threadIdx.x & 63;
  int n = blockIdx.x * 4 + (threadIdx.x >> 6);
  if (n >= NN) return;  // NN % 4 == 0: whole wave exits together, no barrier below
  int beg = row_ptr[n], end = row_ptr[n + 1];
  int deg = end - beg;
  float a0 = 0.f, a1 = 0.f, a2 = 0.f, a3 = 0.f,
        a4 = 0.f, a5 = 0.f, a6 = 0.f, a7 = 0.f;
  for (int base = 0; base < deg; base += 64) {
    int lim = deg - base; if (lim > 64) lim = 64;
    int c = (base + lane < deg) ? col[beg + base + lane] : 0;
    int k = 0;
    for (; k + 8 <= lim; k += 8) {
      int c0 = __shfl(c, k + 0), c1 = __shfl(c, k + 1);
      int c2 = __shfl(c, k + 2), c3 = __shfl(c, k + 3);
      int c4 = __shfl(c, k + 4), c5 = __shfl(c, k + 5);
      int c6 = __shfl(c, k + 6), c7 = __shfl(c, k + 7);
      a0 += h0[c0 * HG + lane]; a1 += h0[c1 * HG + lane];
      a2 += h0[c2 * HG + lane]; a3 += h0[c3 * HG + lane];
      a4 += h0[c4 * HG + lane]; a5 += h0[c5 * HG + lane];
      a6 += h0[c6 * HG + lane]; a7 += h0[c7 * HG + lane];
    }
    for (; k < lim; k++) a0 += h0[__shfl(c, k) * HG + lane];
  }
  float aggv = (((a0 + a1) + (a2 + a3)) + ((a4 + a5) + (a6 + a7))) * deg_inv[n];
  float hv = h0[n * HG + lane];
  float acc = b1[lane];
  #pragma unroll 8
  for (int k = 0; k < HG; k++) {
    float ak = __shfl(aggv, k, 64);
    float hk = __shfl(hv, k, 64);
    acc += ak * Wl[k * HG + lane] + hk * Wr[k * HG + lane];
  }
  float mu = wave_sum64(acc) * (1.f / 64.f);
  float d = acc - mu;
  float var = wave_sum64(d * d) * (1.f / 64.f);
  float o = d * rsqrtf(var + LN_EPS) * g1[lane] + be1[lane];
  o = fmaxf(o, 0.f);
  unsigned short hi = f2bf(o);
  Ht_hi[n * HG + lane] = hi;
  Ht_lo[n * HG + lane] = f2bf(o - bf2f(hi));
}

// ---------------- fused GRU step: gi + gh GEMMs (split-bf16 MFMA) + gates ----------------
// block = 256 threads = 4 waves, handles 16 nodes x all 384 gate outputs.
// wave w computes 6 G-tiles of 16x16 via mfma_f32_16x16x32_bf16.
__global__ __launch_bounds__(256) void k_gru_step(
    const unsigned short* __restrict__ Ahi, const unsigned short* __restrict__ Alo,  // Ht planes (NN x 64)
    const unsigned short* __restrict__ Wih_hi, const unsigned short* __restrict__ Wih_lo, // 384 x 64
    const unsigned short* __restrict__ Hhi, const unsigned short* __restrict__ Hlo,  // h planes (NN x 128)
    const unsigned short* __restrict__ Whh_hi, const unsigned short* __restrict__ Whh_lo, // 384 x 128
    const float* __restrict__ bih, const float* __restrict__ bhh,
    float* __restrict__ h, unsigned short* __restrict__ h_hi, unsigned short* __restrict__ h_lo) {
  __shared__ float gi_s[16][NG + 1];
  __shared__ float gh_s[16][NG + 1];
  int tid = threadIdx.x;
  int lane = tid & 63, wave = tid >> 6;
  int m0 = blockIdx.x * 16;
  int col16 = lane & 15, quad = lane >> 4;
  int mrow = m0 + col16;

  f32x4 acc_gi[6], acc_gh[6];
  #pragma unroll
  for (int t = 0; t < 6; t++) {
    acc_gi[t] = (f32x4){0.f, 0.f, 0.f, 0.f};
    acc_gh[t] = (f32x4){0.f, 0.f, 0.f, 0.f};
  }

  // gi = Ht @ Wih^T : K = 64 (2 chunks of 32)
  #pragma unroll
  for (int kk = 0; kk < HG; kk += 32) {
    bf16x8 ah = *(const bf16x8*)&Ahi[mrow * HG + kk + quad * 8];
    bf16x8 al = *(const bf16x8*)&Alo[mrow * HG + kk + quad * 8];
    #pragma unroll
    for (int t = 0; t < 6; t++) {
      int g = (wave * 6 + t) * 16 + col16;
      bf16x8 bh = *(const bf16x8*)&Wih_hi[g * HG + kk + quad * 8];
      bf16x8 bl = *(const bf16x8*)&Wih_lo[g * HG + kk + quad * 8];
      acc_gi[t] = __builtin_amdgcn_mfma_f32_16x16x32_bf16(ah, bh, acc_gi[t], 0, 0, 0);
      acc_gi[t] = __builtin_amdgcn_mfma_f32_16x16x32_bf16(al, bh, acc_gi[t], 0, 0, 0);
      acc_gi[t] = __builtin_amdgcn_mfma_f32_16x16x32_bf16(ah, bl, acc_gi[t], 0, 0, 0);
    }
  }
  // gh = h @ Whh^T : K = 128 (4 chunks of 32)
  #pragma unroll
  for (int kk = 0; kk < HTT; kk += 32) {
    bf16x8 ah = *(const bf16x8*)&Hhi[mrow * HTT + kk + quad * 8];
    bf16x8 al = *(const bf16x8*)&Hlo[mrow * HTT + kk + quad * 8];
    #pragma unroll
    for (int t = 0; t < 6; t++) {
      int g = (wave * 6 + t) * 16 + col16;
      bf16x8 bh = *(const bf16x8*)&Whh_hi[g * HTT + kk + quad * 8];
      bf16x8 bl = *(const bf16x8*)&Whh_lo[g * HTT + kk + quad * 8];
      acc_gh[t] = __builtin_amdgcn_mfma_f32_16x16x32_bf16(ah, bh, acc_gh[t], 0, 0, 0);
      acc_gh[t] = __builtin_amdgcn_mfma_f32_16x16x32_bf16(al, bh, acc_gh[t], 0, 0, 0);
      acc_gh[t] = __builtin_amdgcn_mfma_f32_16x16x32_bf16(ah, bl, acc_gh[t], 0, 0, 0);
    }
  }
  // C/D layout: col = lane&15 (g), row = quad*4 + reg (m)
  #pragma unroll
  for (int t = 0; t < 6; t++) {
    int g = (wave * 6 + t) * 16 + col16;
    #pragma unroll
    for (int r = 0; r < 4; r++) {
      int m = quad * 4 + r;
      gi_s[m][g] = acc_gi[t][r];
      gh_s[m][g] = acc_gh[t][r];
    }
  }
  __syncthreads();
  // gate update: 16 nodes x 128 = 2048 elems, 8 per thread
  #pragma unroll
  for (int i = 0; i < 8; i++) {
    int idx = i * 256 + tid;
    int nl = idx >> 7, j = idx & 127;
    int n = m0 + nl;
    float gr = gi_s[nl][j] + bih[j] + gh_s[nl][j] + bhh[j];
    float gz = gi_s[nl][HTT + j] + bih[HTT + j] + gh_s[nl][HTT + j] + bhh[HTT + j];
    float gin = gi_s[nl][2 * HTT + j] + bih[2 * HTT + j];
    float ghn = gh_s[nl][2 * HTT + j] + bhh[2 * HTT + j];
    float r = 1.f / (1.f + __expf(-gr));
    float z = 1.f / (1.f + __expf(-gz));
    float nn = tanhf(gin + r * ghn);
    float ho = h[n * HTT + j];
    float hn = (1.f - z) * nn + z * ho;
    h[n * HTT + j] = hn;
    unsigned short hh = f2bf(hn);
    h_hi[n * HTT + j] = hh;
    h_lo[n * HTT + j] = f2bf(hn - bf2f(hh));
  }
}

// ---------------- head ----------------
__global__ __launch_bounds__(256) void k_head(
    const float* __restrict__ h, const float* __restrict__ hw,
    const float* __restrict__ hb, float* __restrict__ out) {
  int lane = threadIdx.x & 63;
  int n = blockIdx.x * 4 + (threadIdx.x >> 6);
  if (n >= NN) return;
  float v = h[n * HTT + lane] * hw[lane] + h[n * HTT + 64 + lane] * hw[64 + lane];
  v = wave_sum64(v);
  if (lane == 0) out[n] = v + hb[0];
}

extern "C" void kernel_launch(void* const* d_in, const int* in_sizes, int n_in,
                              void* d_out, int out_size, void* d_ws, size_t ws_size,
                              hipStream_t stream) {
  const float* x_seq = (const float*)d_in[0];
  const int*   edge  = (const int*)d_in[1];
  const float* Wl0   = (const float*)d_in[2];
  const float* Wr0   = (const float*)d_in[3];
  const float* b0    = (const float*)d_in[4];
  const float* g0    = (const float*)d_in[5];
  const float* be0   = (const float*)d_in[6];
  const float* Wl1   = (const float*)d_in[7];
  const float* Wr1   = (const float*)d_in[8];
  const float* b1    = (const float*)d_in[9];
  const float* g1    = (const float*)d_in[10];
  const float* be1   = (const float*)d_in[11];
  const float* Wih   = (const float*)d_in[12];
  const float* Whh   = (const float*)d_in[13];
  const float* bih   = (const float*)d_in[14];
  const float* bhh   = (const float*)d_in[15];
  const float* headW = (const float*)d_in[16];
  const float* headb = (const float*)d_in[17];
  float* out = (float*)d_out;

  const int* srcp = edge;
  const int* dstp = edge + NE;

  char* ws = (char*)d_ws;
  size_t off = 0;
  auto alloc = [&](size_t bytes) -> void* {
    void* p = ws + off;
    off += (bytes + 255) & ~(size_t)255;
    return p;
  };
  int*   cnt     = (int*)alloc(NN * 4);
  int*   row_ptr = (int*)alloc((NN + 1) * 4);
  int*   col     = (int*)alloc(NE * 4);
  float* deg_inv = (float*)alloc(NN * 4);
  float* h0      = (float*)alloc((size_t)NN * HG * 4);
  unsigned short* Ht_hi = (unsigned short*)alloc((size_t)NN * HG * 2);
  unsigned short* Ht_lo = (unsigned short*)alloc((size_t)NN * HG * 2);
  float* h       = (float*)alloc((size_t)NN * HTT * 4);
  unsigned short* h_hi = (unsigned short*)alloc((size_t)NN * HTT * 2);
  unsigned short* h_lo = (unsigned short*)alloc((size_t)NN * HTT * 2);
  unsigned short* Wih_hi = (unsigned short*)alloc((size_t)NG * HG * 2);
  unsigned short* Wih_lo = (unsigned short*)alloc((size_t)NG * HG * 2);
  unsigned short* Whh_hi = (unsigned short*)alloc((size_t)NG * HTT * 2);
  unsigned short* Whh_lo = (unsigned short*)alloc((size_t)NG * HTT * 2);
  (void)ws_size; (void)in_sizes; (void)n_in; (void)out_size;

  k_init<<<512, 256, 0, stream>>>(cnt, h, h_hi, h_lo);
  k_hist<<<(NE + 255) / 256, 256, 0, stream>>>(dstp, cnt);
  k_scan<<<1, 1024, 0, stream>>>(cnt, row_ptr, deg_inv);
  k_fill<<<(NE + 255) / 256, 256, 0, stream>>>(srcp, dstp, cnt, col);
  k_cvt<<<(NG * HG + 255) / 256, 256, 0, stream>>>(Wih, Wih_hi, Wih_lo, NG * HG);
  k_cvt<<<(NG * HTT + 255) / 256, 256, 0, stream>>>(Whh, Whh_hi, Whh_lo, NG * HTT);

  for (int t = 0; t < TS; t++) {
    const float* x_t = x_seq + (size_t)t * NN;
    k_sage0<<<5000, 256, 0, stream>>>(x_t, row_ptr, col, deg_inv,
                                      Wl0, Wr0, b0, g0, be0, h0);
    k_sage1<<<5000, 256, 0, stream>>>(h0, row_ptr, col, deg_inv,
                                      Wl1, Wr1, b1, g1, be1, Ht_hi, Ht_lo);
    k_gru_step<<<NN / 16, 256, 0, stream>>>(Ht_hi, Ht_lo, Wih_hi, Wih_lo,
                                            h_hi, h_lo, Whh_hi, Whh_lo,
                                            bih, bhh, h, h_hi, h_lo);
  }
  k_head<<<5000, 256, 0, stream>>>(h, headW, headb, out);
}

// Round 3
// 1897.463 us; speedup vs baseline: 1.4019x; 1.0537x over previous
//
#include <hip/hip_runtime.h>
#include <math.h>

#define NN 20000
#define NE 320000
#define TS 16
#define HG 64
#define HTT 128
#define NG 384   // 3*HT
#define LN_EPS 1e-5f

typedef __attribute__((ext_vector_type(8))) short bf16x8;
typedef __attribute__((ext_vector_type(4))) float f32x4;

__device__ __forceinline__ float wave_sum64(float v) {
  #pragma unroll
  for (int off = 32; off > 0; off >>= 1) v += __shfl_xor(v, off, 64);
  return v;
}

__device__ __forceinline__ unsigned short f2bf(float x) {
  unsigned u = __float_as_uint(x);
  unsigned r = u + 0x7FFFu + ((u >> 16) & 1u);   // round-nearest-even to bf16
  return (unsigned short)(r >> 16);
}
__device__ __forceinline__ float bf2f(unsigned short h) {
  return __uint_as_float(((unsigned)h) << 16);
}

// ---------------- setup ----------------
__global__ void k_init(int* cnt, float* h, unsigned short* h_hi, unsigned short* h_lo) {
  int i = blockIdx.x * blockDim.x + threadIdx.x;
  int stride = gridDim.x * blockDim.x;
  for (int j = i; j < NN; j += stride) cnt[j] = 0;
  for (int j = i; j < NN * HTT; j += stride) {
    h[j] = 0.f; h_hi[j] = 0; h_lo[j] = 0;
  }
}

__global__ void k_hist(const int* __restrict__ dst, int* cnt) {
  int e = blockIdx.x * blockDim.x + threadIdx.x;
  if (e < NE) atomicAdd(&cnt[dst[e]], 1);
}

__global__ void k_scan(int* cnt, int* row_ptr, float* deg_inv) {
  __shared__ int s[1024];
  int tid = threadIdx.x;
  int carry = 0;
  for (int base = 0; base < NN; base += 1024) {
    int n = base + tid;
    int v = (n < NN) ? cnt[n] : 0;
    s[tid] = v;
    __syncthreads();
    for (int off = 1; off < 1024; off <<= 1) {
      int t = (tid >= off) ? s[tid - off] : 0;
      __syncthreads();
      s[tid] += t;
      __syncthreads();
    }
    int incl = s[tid];
    if (n < NN) {
      int excl = carry + incl - v;
      row_ptr[n] = excl;
      cnt[n] = excl;
      deg_inv[n] = 1.0f / (float)((v > 1) ? v : 1);
    }
    carry += s[1023];
    __syncthreads();
  }
  if (tid == 0) row_ptr[NN] = carry;
}

__global__ void k_fill(const int* __restrict__ src, const int* __restrict__ dst,
                       int* cursor, int* col) {
  int e = blockIdx.x * blockDim.x + threadIdx.x;
  if (e < NE) {
    int p = atomicAdd(&cursor[dst[e]], 1);
    col[p] = src[e];
  }
}

__global__ void k_cvt(const float* __restrict__ w, unsigned short* __restrict__ hi,
                      unsigned short* __restrict__ lo, int n) {
  int i = blockIdx.x * blockDim.x + threadIdx.x;
  if (i < n) {
    float x = w[i];
    unsigned short h = f2bf(x);
    hi[i] = h;
    lo[i] = f2bf(x - bf2f(h));
  }
}

// ---------------- SAGE layer 0 (F=1 -> HG) ----------------
__global__ __launch_bounds__(256) void k_sage0(
    const float* __restrict__ x_t,
    const int* __restrict__ row_ptr, const int* __restrict__ col,
    const float* __restrict__ deg_inv,
    const float* __restrict__ Wl0, const float* __restrict__ Wr0,
    const float* __restrict__ b0,
    const float* __restrict__ g0, const float* __restrict__ be0,
    float* __restrict__ h0) {
  int lane = threadIdx.x & 63;
  int n = blockIdx.x * 4 + (threadIdx.x >> 6);
  if (n >= NN) return;
  int beg = row_ptr[n], end = row_ptr[n + 1];
  float s = 0.f;
  for (int e = beg + lane; e < end; e += 64) s += x_t[col[e]];
  float a = wave_sum64(s) * deg_inv[n];
  float xn = x_t[n];
  float v = a * Wl0[lane] + xn * Wr0[lane] + b0[lane];
  float mu = wave_sum64(v) * (1.f / 64.f);
  float d = v - mu;
  float var = wave_sum64(d * d) * (1.f / 64.f);
  float o = d * rsqrtf(var + LN_EPS) * g0[lane] + be0[lane];
  h0[n * HG + lane] = fmaxf(o, 0.f);
}

// ---------------- SAGE layer 1 (HG -> HG), ILP-unrolled gather ----------------
__global__ __launch_bounds__(256) void k_sage1(
    const float* __restrict__ h0,
    const int* __restrict__ row_ptr, const int* __restrict__ col,
    const float* __restrict__ deg_inv,
    const float* __restrict__ Wl1, const float* __restrict__ Wr1,
    const float* __restrict__ b1,
    const float* __restrict__ g1, const float* __restrict__ be1,
    unsigned short* __restrict__ Ht_hi, unsigned short* __restrict__ Ht_lo) {
  __shared__ float Wl[HG * HG];
  __shared__ float Wr[HG * HG];
  for (int i = threadIdx.x * 4; i < HG * HG; i += 1024) {
    *(float4*)&Wl[i] = *(const float4*)&Wl1[i];
    *(float4*)&Wr[i] = *(const float4*)&Wr1[i];
  }
  __syncthreads();
  int lane = threadIdx.x & 63;
  int n = blockIdx.x * 4 + (threadIdx.x >> 6);
  if (n >= NN) return;  // NN % 4 == 0: whole wave exits together
  int beg = row_ptr[n], end = row_ptr[n + 1];
  int deg = end - beg;
  float a0 = 0.f, a1 = 0.f, a2 = 0.f, a3 = 0.f,
        a4 = 0.f, a5 = 0.f, a6 = 0.f, a7 = 0.f;
  for (int base = 0; base < deg; base += 64) {
    int lim = deg - base; if (lim > 64) lim = 64;
    int c = (base + lane < deg) ? col[beg + base + lane] : 0;
    int k = 0;
    for (; k + 8 <= lim; k += 8) {
      int c0 = __shfl(c, k + 0), c1 = __shfl(c, k + 1);
      int c2 = __shfl(c, k + 2), c3 = __shfl(c, k + 3);
      int c4 = __shfl(c, k + 4), c5 = __shfl(c, k + 5);
      int c6 = __shfl(c, k + 6), c7 = __shfl(c, k + 7);
      a0 += h0[c0 * HG + lane]; a1 += h0[c1 * HG + lane];
      a2 += h0[c2 * HG + lane]; a3 += h0[c3 * HG + lane];
      a4 += h0[c4 * HG + lane]; a5 += h0[c5 * HG + lane];
      a6 += h0[c6 * HG + lane]; a7 += h0[c7 * HG + lane];
    }
    for (; k < lim; k++) a0 += h0[__shfl(c, k) * HG + lane];
  }
  float aggv = (((a0 + a1) + (a2 + a3)) + ((a4 + a5) + (a6 + a7))) * deg_inv[n];
  float hv = h0[n * HG + lane];
  float acc = b1[lane];
  #pragma unroll 8
  for (int k = 0; k < HG; k++) {
    float ak = __shfl(aggv, k, 64);
    float hk = __shfl(hv, k, 64);
    acc += ak * Wl[k * HG + lane] + hk * Wr[k * HG + lane];
  }
  float mu = wave_sum64(acc) * (1.f / 64.f);
  float d = acc - mu;
  float var = wave_sum64(d * d) * (1.f / 64.f);
  float o = d * rsqrtf(var + LN_EPS) * g1[lane] + be1[lane];
  o = fmaxf(o, 0.f);
  unsigned short hi = f2bf(o);
  Ht_hi[n * HG + lane] = hi;
  Ht_lo[n * HG + lane] = f2bf(o - bf2f(hi));
}

// ---------------- fused GRU step v3: M=64/block, gate-aligned tiles, no LDS ----------------
// 4 waves; wave w owns gate cols j in [32w, 32w+32):
//   r: g-tiles {2w, 2w+1}  (g = j)
//   z: g-tiles {8+2w, 9+2w} (g = 128+j)  -> gi+gh share accumulators with r,z
//   n: g-tiles {16+2w, 17+2w} (g = 256+j) -> Ni (gi) and Nh (gh) kept separate
// acc[8][mt]: 0,1=r  2,3=z  4,5=Ni  6,7=Nh
__global__ __launch_bounds__(256) void k_gru_step(
    const unsigned short* __restrict__ Ahi, const unsigned short* __restrict__ Alo,   // Ht planes (NN x 64)
    const unsigned short* __restrict__ Wih_hi, const unsigned short* __restrict__ Wih_lo, // 384 x 64
    const unsigned short* __restrict__ Hhi, const unsigned short* __restrict__ Hlo,   // h planes (NN x 128)
    const unsigned short* __restrict__ Whh_hi, const unsigned short* __restrict__ Whh_lo, // 384 x 128
    const float* __restrict__ bih, const float* __restrict__ bhh,
    float* __restrict__ h, unsigned short* __restrict__ h_hi, unsigned short* __restrict__ h_lo) {
  int tid = threadIdx.x;
  int lane = tid & 63, wave = tid >> 6;
  int col16 = lane & 15, quad = lane >> 4;
  int m0 = blockIdx.x * 64;
  int gb = 2 * wave;           // base j-tile for this wave

  f32x4 acc[8][4];
  #pragma unroll
  for (int a = 0; a < 8; a++)
    #pragma unroll
    for (int mt = 0; mt < 4; mt++) acc[a][mt] = (f32x4){0.f, 0.f, 0.f, 0.f};

  // ---- phase gi: A = Ht (K=64), W = Wih ----
  #pragma unroll
  for (int kk = 0; kk < HG; kk += 32) {
    bf16x8 ah[4], al[4];
    #pragma unroll
    for (int mt = 0; mt < 4; mt++) {
      int row = m0 + mt * 16 + col16;
      if (row >= NN) row = NN - 1;
      size_t o = (size_t)row * HG + kk + quad * 8;
      ah[mt] = *(const bf16x8*)&Ahi[o];
      al[mt] = *(const bf16x8*)&Alo[o];
    }
    #pragma unroll
    for (int t6 = 0; t6 < 6; t6++) {
      int gt = (t6 < 2) ? (gb + t6) : (t6 < 4) ? (8 + gb + t6 - 2) : (16 + gb + t6 - 4);
      int g = gt * 16 + col16;
      size_t o = (size_t)g * HG + kk + quad * 8;
      bf16x8 bh = *(const bf16x8*)&Wih_hi[o];
      bf16x8 bl = *(const bf16x8*)&Wih_lo[o];
      #pragma unroll
      for (int mt = 0; mt < 4; mt++) {
        acc[t6][mt] = __builtin_amdgcn_mfma_f32_16x16x32_bf16(ah[mt], bh, acc[t6][mt], 0, 0, 0);
        acc[t6][mt] = __builtin_amdgcn_mfma_f32_16x16x32_bf16(al[mt], bh, acc[t6][mt], 0, 0, 0);
        acc[t6][mt] = __builtin_amdgcn_mfma_f32_16x16x32_bf16(ah[mt], bl, acc[t6][mt], 0, 0, 0);
      }
    }
  }
  // ---- phase gh: A = h (K=128), W = Whh ----
  #pragma unroll
  for (int kk = 0; kk < HTT; kk += 32) {
    bf16x8 ah[4], al[4];
    #pragma unroll
    for (int mt = 0; mt < 4; mt++) {
      int row = m0 + mt * 16 + col16;
      if (row >= NN) row = NN - 1;
      size_t o = (size_t)row * HTT + kk + quad * 8;
      ah[mt] = *(const bf16x8*)&Hhi[o];
      al[mt] = *(const bf16x8*)&Hlo[o];
    }
    #pragma unroll
    for (int t6 = 0; t6 < 6; t6++) {
      int gt = (t6 < 2) ? (gb + t6) : (t6 < 4) ? (8 + gb + t6 - 2) : (16 + gb + t6 - 4);
      int ai = (t6 < 4) ? t6 : t6 + 2;        // n-part of gh -> acc[6],acc[7]
      int g = gt * 16 + col16;
      size_t o = (size_t)g * HTT + kk + quad * 8;
      bf16x8 bh = *(const bf16x8*)&Whh_hi[o];
      bf16x8 bl = *(const bf16x8*)&Whh_lo[o];
      #pragma unroll
      for (int mt = 0; mt < 4; mt++) {
        acc[ai][mt] = __builtin_amdgcn_mfma_f32_16x16x32_bf16(ah[mt], bh, acc[ai][mt], 0, 0, 0);
        acc[ai][mt] = __builtin_amdgcn_mfma_f32_16x16x32_bf16(al[mt], bh, acc[ai][mt], 0, 0, 0);
        acc[ai][mt] = __builtin_amdgcn_mfma_f32_16x16x32_bf16(ah[mt], bl, acc[ai][mt], 0, 0, 0);
      }
    }
  }

  // ---- gates in registers: lane holds (m = m0+mt*16+quad*4+reg, j = (gb+js)*16+col16) ----
  int jj[2]; float bR[2], bZ[2], bNi[2], bNh[2];
  #pragma unroll
  for (int js = 0; js < 2; js++) {
    int j = (gb + js) * 16 + col16;
    jj[js] = j;
    bR[js]  = bih[j] + bhh[j];
    bZ[js]  = bih[HTT + j] + bhh[HTT + j];
    bNi[js] = bih[2 * HTT + j];
    bNh[js] = bhh[2 * HTT + j];
  }
  #pragma unroll
  for (int mt = 0; mt < 4; mt++) {
    #pragma unroll
    for (int r = 0; r < 4; r++) {
      int m = m0 + mt * 16 + quad * 4 + r;
      if (m < NN) {
        #pragma unroll
        for (int js = 0; js < 2; js++) {
          int j = jj[js];
          float R  = acc[0 + js][mt][r] + bR[js];
          float Z  = acc[2 + js][mt][r] + bZ[js];
          float Ni = acc[4 + js][mt][r] + bNi[js];
          float Nh = acc[6 + js][mt][r] + bNh[js];
          float rg = 1.f / (1.f + __expf(-R));
          float zg = 1.f / (1.f + __expf(-Z));
          float x = Ni + rg * Nh;
          float e = __expf(-2.f * fabsf(x));
          float th = (1.f - e) / (1.f + e);
          float nn = copysignf(th, x);
          size_t idx = (size_t)m * HTT + j;
          float hn = (1.f - zg) * nn + zg * h[idx];
          h[idx] = hn;
          unsigned short hh = f2bf(hn);
          h_hi[idx] = hh;
          h_lo[idx] = f2bf(hn - bf2f(hh));
        }
      }
    }
  }
}

// ---------------- head ----------------
__global__ __launch_bounds__(256) void k_head(
    const float* __restrict__ h, const float* __restrict__ hw,
    const float* __restrict__ hb, float* __restrict__ out) {
  int lane = threadIdx.x & 63;
  int n = blockIdx.x * 4 + (threadIdx.x >> 6);
  if (n >= NN) return;
  float v = h[n * HTT + lane] * hw[lane] + h[n * HTT + 64 + lane] * hw[64 + lane];
  v = wave_sum64(v);
  if (lane == 0) out[n] = v + hb[0];
}

extern "C" void kernel_launch(void* const* d_in, const int* in_sizes, int n_in,
                              void* d_out, int out_size, void* d_ws, size_t ws_size,
                              hipStream_t stream) {
  const float* x_seq = (const float*)d_in[0];
  const int*   edge  = (const int*)d_in[1];
  const float* Wl0   = (const float*)d_in[2];
  const float* Wr0   = (const float*)d_in[3];
  const float* b0    = (const float*)d_in[4];
  const float* g0    = (const float*)d_in[5];
  const float* be0   = (const float*)d_in[6];
  const float* Wl1   = (const float*)d_in[7];
  const float* Wr1   = (const float*)d_in[8];
  const float* b1    = (const float*)d_in[9];
  const float* g1    = (const float*)d_in[10];
  const float* be1   = (const float*)d_in[11];
  const float* Wih   = (const float*)d_in[12];
  const float* Whh   = (const float*)d_in[13];
  const float* bih   = (const float*)d_in[14];
  const float* bhh   = (const float*)d_in[15];
  const float* headW = (const float*)d_in[16];
  const float* headb = (const float*)d_in[17];
  float* out = (float*)d_out;

  const int* srcp = edge;
  const int* dstp = edge + NE;

  char* ws = (char*)d_ws;
  size_t off = 0;
  auto alloc = [&](size_t bytes) -> void* {
    void* p = ws + off;
    off += (bytes + 255) & ~(size_t)255;
    return p;
  };
  int*   cnt     = (int*)alloc(NN * 4);
  int*   row_ptr = (int*)alloc((NN + 1) * 4);
  int*   col     = (int*)alloc(NE * 4);
  float* deg_inv = (float*)alloc(NN * 4);
  float* h0      = (float*)alloc((size_t)NN * HG * 4);
  unsigned short* Ht_hi = (unsigned short*)alloc((size_t)NN * HG * 2);
  unsigned short* Ht_lo = (unsigned short*)alloc((size_t)NN * HG * 2);
  float* h       = (float*)alloc((size_t)NN * HTT * 4);
  unsigned short* h_hi = (unsigned short*)alloc((size_t)NN * HTT * 2);
  unsigned short* h_lo = (unsigned short*)alloc((size_t)NN * HTT * 2);
  unsigned short* Wih_hi = (unsigned short*)alloc((size_t)NG * HG * 2);
  unsigned short* Wih_lo = (unsigned short*)alloc((size_t)NG * HG * 2);
  unsigned short* Whh_hi = (unsigned short*)alloc((size_t)NG * HTT * 2);
  unsigned short* Whh_lo = (unsigned short*)alloc((size_t)NG * HTT * 2);
  (void)ws_size; (void)in_sizes; (void)n_in; (void)out_size;

  k_init<<<512, 256, 0, stream>>>(cnt, h, h_hi, h_lo);
  k_hist<<<(NE + 255) / 256, 256, 0, stream>>>(dstp, cnt);
  k_scan<<<1, 1024, 0, stream>>>(cnt, row_ptr, deg_inv);
  k_fill<<<(NE + 255) / 256, 256, 0, stream>>>(srcp, dstp, cnt, col);
  k_cvt<<<(NG * HG + 255) / 256, 256, 0, stream>>>(Wih, Wih_hi, Wih_lo, NG * HG);
  k_cvt<<<(NG * HTT + 255) / 256, 256, 0, stream>>>(Whh, Whh_hi, Whh_lo, NG * HTT);

  for (int t = 0; t < TS; t++) {
    const float* x_t = x_seq + (size_t)t * NN;
    k_sage0<<<5000, 256, 0, stream>>>(x_t, row_ptr, col, deg_inv,
                                      Wl0, Wr0, b0, g0, be0, h0);
    k_sage1<<<5000, 256, 0, stream>>>(h0, row_ptr, col, deg_inv,
                                      Wl1, Wr1, b1, g1, be1, Ht_hi, Ht_lo);
    k_gru_step<<<(NN + 63) / 64, 256, 0, stream>>>(Ht_hi, Ht_lo, Wih_hi, Wih_lo,
                                                   h_hi, h_lo, Whh_hi, Whh_lo,
                                                   bih, bhh, h, h_hi, h_lo);
  }
  k_head<<<5000, 256, 0, stream>>>(h, headW, headb, out);
}

// Round 4
// 1413.874 us; speedup vs baseline: 1.8814x; 1.3420x over previous
//
#include <hip/hip_runtime.h>
#include <math.h>

#define NN 20000
#define NE 320000
#define TS 16
#define HG 64
#define HTT 128
#define NG 384   // 3*HT
#define LN_EPS 1e-5f

typedef __attribute__((ext_vector_type(8))) short bf16x8;
typedef __attribute__((ext_vector_type(4))) float f32x4;

__device__ __forceinline__ float wave_sum64(float v) {
  #pragma unroll
  for (int off = 32; off > 0; off >>= 1) v += __shfl_xor(v, off, 64);
  return v;
}
__device__ __forceinline__ float quad_sum16(float v) {
  #pragma unroll
  for (int off = 1; off < 16; off <<= 1) v += __shfl_xor(v, off, 64);
  return v;
}

__device__ __forceinline__ unsigned short f2bf(float x) {
  unsigned u = __float_as_uint(x);
  unsigned r = u + 0x7FFFu + ((u >> 16) & 1u);   // RNE to bf16
  return (unsigned short)(r >> 16);
}
__device__ __forceinline__ float bf2f(unsigned short h) {
  return __uint_as_float(((unsigned)h) << 16);
}

// ---------------- setup ----------------
__global__ void k_init(int* cnt, float* h, unsigned short* h_hi, unsigned short* h_lo) {
  int i = blockIdx.x * blockDim.x + threadIdx.x;
  int stride = gridDim.x * blockDim.x;
  for (int j = i; j < NN; j += stride) cnt[j] = 0;
  for (int j = i; j < NN * HTT; j += stride) {
    h[j] = 0.f; h_hi[j] = 0; h_lo[j] = 0;
  }
}

__global__ void k_hist(const int* __restrict__ dst, int* cnt) {
  int e = blockIdx.x * blockDim.x + threadIdx.x;
  if (e < NE) atomicAdd(&cnt[dst[e]], 1);
}

__global__ void k_scan(int* cnt, int* row_ptr, float* deg_inv) {
  __shared__ int s[1024];
  int tid = threadIdx.x;
  int carry = 0;
  for (int base = 0; base < NN; base += 1024) {
    int n = base + tid;
    int v = (n < NN) ? cnt[n] : 0;
    s[tid] = v;
    __syncthreads();
    for (int off = 1; off < 1024; off <<= 1) {
      int t = (tid >= off) ? s[tid - off] : 0;
      __syncthreads();
      s[tid] += t;
      __syncthreads();
    }
    int incl = s[tid];
    if (n < NN) {
      int excl = carry + incl - v;
      row_ptr[n] = excl;
      cnt[n] = excl;
      deg_inv[n] = 1.0f / (float)((v > 1) ? v : 1);
    }
    carry += s[1023];
    __syncthreads();
  }
  if (tid == 0) row_ptr[NN] = carry;
}

__global__ void k_fill(const int* __restrict__ src, const int* __restrict__ dst,
                       int* cursor, int* col) {
  int e = blockIdx.x * blockDim.x + threadIdx.x;
  if (e < NE) {
    int p = atomicAdd(&cursor[dst[e]], 1);
    col[p] = src[e];
  }
}

__global__ void k_cvt(const float* __restrict__ w, unsigned short* __restrict__ hi,
                      unsigned short* __restrict__ lo, int n) {
  int i = blockIdx.x * blockDim.x + threadIdx.x;
  if (i < n) {
    float x = w[i];
    unsigned short h = f2bf(x);
    hi[i] = h;
    lo[i] = f2bf(x - bf2f(h));
  }
}

// combined sage weight, transposed: Wc[n][k], k<64 -> Wl1[k][n], else Wr1[k-64][n]
__global__ void k_cvt_sage(const float* __restrict__ Wl1, const float* __restrict__ Wr1,
                           unsigned short* __restrict__ hi, unsigned short* __restrict__ lo) {
  int i = blockIdx.x * blockDim.x + threadIdx.x;   // i = n*128 + k
  if (i < HG * 128) {
    int n = i >> 7, k = i & 127;
    float x = (k < HG) ? Wl1[k * HG + n] : Wr1[(k - HG) * HG + n];
    unsigned short h = f2bf(x);
    hi[i] = h;
    lo[i] = f2bf(x - bf2f(h));
  }
}

// ---------------- SAGE layer 0 (F=1 -> HG): fp32 + split planes ----------------
__global__ __launch_bounds__(256) void k_sage0(
    const float* __restrict__ x_t,
    const int* __restrict__ row_ptr, const int* __restrict__ col,
    const float* __restrict__ deg_inv,
    const float* __restrict__ Wl0, const float* __restrict__ Wr0,
    const float* __restrict__ b0,
    const float* __restrict__ g0, const float* __restrict__ be0,
    float* __restrict__ h0f, unsigned short* __restrict__ h0hi, unsigned short* __restrict__ h0lo) {
  int lane = threadIdx.x & 63;
  int n = blockIdx.x * 4 + (threadIdx.x >> 6);
  if (n >= NN) return;
  int beg = row_ptr[n], end = row_ptr[n + 1];
  float s = 0.f;
  for (int e = beg + lane; e < end; e += 64) s += x_t[col[e]];
  float a = wave_sum64(s) * deg_inv[n];
  float xn = x_t[n];
  float v = a * Wl0[lane] + xn * Wr0[lane] + b0[lane];
  float mu = wave_sum64(v) * (1.f / 64.f);
  float d = v - mu;
  float var = wave_sum64(d * d) * (1.f / 64.f);
  float o = d * rsqrtf(var + LN_EPS) * g0[lane] + be0[lane];
  o = fmaxf(o, 0.f);
  h0f[n * HG + lane] = o;
  unsigned short hh = f2bf(o);
  h0hi[n * HG + lane] = hh;
  h0lo[n * HG + lane] = f2bf(o - bf2f(hh));
}

// ---------------- gather: agg = mean of neighbor h0 rows -> split planes ----------------
__global__ __launch_bounds__(256) void k_gather(
    const float* __restrict__ h0f,
    const int* __restrict__ row_ptr, const int* __restrict__ col,
    const float* __restrict__ deg_inv,
    unsigned short* __restrict__ agghi, unsigned short* __restrict__ agglo) {
  int lane = threadIdx.x & 63;
  int n = blockIdx.x * 4 + (threadIdx.x >> 6);
  if (n >= NN) return;
  int beg = row_ptr[n], end = row_ptr[n + 1];
  int deg = end - beg;
  float a0 = 0.f, a1 = 0.f, a2 = 0.f, a3 = 0.f,
        a4 = 0.f, a5 = 0.f, a6 = 0.f, a7 = 0.f;
  for (int base = 0; base < deg; base += 64) {
    int lim = deg - base; if (lim > 64) lim = 64;
    int c = (base + lane < deg) ? col[beg + base + lane] : 0;
    int k = 0;
    for (; k + 8 <= lim; k += 8) {
      int c0 = __shfl(c, k + 0), c1 = __shfl(c, k + 1);
      int c2 = __shfl(c, k + 2), c3 = __shfl(c, k + 3);
      int c4 = __shfl(c, k + 4), c5 = __shfl(c, k + 5);
      int c6 = __shfl(c, k + 6), c7 = __shfl(c, k + 7);
      a0 += h0f[c0 * HG + lane]; a1 += h0f[c1 * HG + lane];
      a2 += h0f[c2 * HG + lane]; a3 += h0f[c3 * HG + lane];
      a4 += h0f[c4 * HG + lane]; a5 += h0f[c5 * HG + lane];
      a6 += h0f[c6 * HG + lane]; a7 += h0f[c7 * HG + lane];
    }
    for (; k < lim; k++) a0 += h0f[__shfl(c, k) * HG + lane];
  }
  float aggv = (((a0 + a1) + (a2 + a3)) + ((a4 + a5) + (a6 + a7))) * deg_inv[n];
  unsigned short hh = f2bf(aggv);
  agghi[n * HG + lane] = hh;
  agglo[n * HG + lane] = f2bf(aggv - bf2f(hh));
}

// ---------------- sage layer-1 GEMM + LN + ReLU via MFMA ----------------
// block = 256 = 4 waves; wave handles 16 nodes (m-tile), all 64 out feats (4 n-tiles).
// C = [agg | h0] @ Wc^T  (K = 128, split-bf16, 3 MFMAs per product)
__global__ __launch_bounds__(256) void k_sage_mm(
    const unsigned short* __restrict__ agghi, const unsigned short* __restrict__ agglo,
    const unsigned short* __restrict__ h0hi, const unsigned short* __restrict__ h0lo,
    const unsigned short* __restrict__ Wchi, const unsigned short* __restrict__ Wclo, // 64 x 128
    const float* __restrict__ b1, const float* __restrict__ g1, const float* __restrict__ be1,
    unsigned short* __restrict__ Ht_hi, unsigned short* __restrict__ Ht_lo) {
  int lane = threadIdx.x & 63, wave = threadIdx.x >> 6;
  int col16 = lane & 15, quad = lane >> 4;
  int m0 = blockIdx.x * 64 + wave * 16;
  int arow = m0 + col16; if (arow >= NN) arow = NN - 1;

  f32x4 acc[4];
  #pragma unroll
  for (int nt = 0; nt < 4; nt++) acc[nt] = (f32x4){0.f, 0.f, 0.f, 0.f};

  // K = 0..63 : agg vs Wc cols 0..63
  #pragma unroll
  for (int kk = 0; kk < HG; kk += 32) {
    bf16x8 ah = *(const bf16x8*)&agghi[arow * HG + kk + quad * 8];
    bf16x8 al = *(const bf16x8*)&agglo[arow * HG + kk + quad * 8];
    #pragma unroll
    for (int nt = 0; nt < 4; nt++) {
      int n = nt * 16 + col16;
      bf16x8 bh = *(const bf16x8*)&Wchi[n * 128 + kk + quad * 8];
      bf16x8 bl = *(const bf16x8*)&Wclo[n * 128 + kk + quad * 8];
      acc[nt] = __builtin_amdgcn_mfma_f32_16x16x32_bf16(ah, bh, acc[nt], 0, 0, 0);
      acc[nt] = __builtin_amdgcn_mfma_f32_16x16x32_bf16(al, bh, acc[nt], 0, 0, 0);
      acc[nt] = __builtin_amdgcn_mfma_f32_16x16x32_bf16(ah, bl, acc[nt], 0, 0, 0);
    }
  }
  // K = 64..127 : h0 vs Wc cols 64..127
  #pragma unroll
  for (int kk = 0; kk < HG; kk += 32) {
    bf16x8 ah = *(const bf16x8*)&h0hi[arow * HG + kk + quad * 8];
    bf16x8 al = *(const bf16x8*)&h0lo[arow * HG + kk + quad * 8];
    #pragma unroll
    for (int nt = 0; nt < 4; nt++) {
      int n = nt * 16 + col16;
      bf16x8 bh = *(const bf16x8*)&Wchi[n * 128 + 64 + kk + quad * 8];
      bf16x8 bl = *(const bf16x8*)&Wclo[n * 128 + 64 + kk + quad * 8];
      acc[nt] = __builtin_amdgcn_mfma_f32_16x16x32_bf16(ah, bh, acc[nt], 0, 0, 0);
      acc[nt] = __builtin_amdgcn_mfma_f32_16x16x32_bf16(al, bh, acc[nt], 0, 0, 0);
      acc[nt] = __builtin_amdgcn_mfma_f32_16x16x32_bf16(ah, bl, acc[nt], 0, 0, 0);
    }
  }

  // bias + LN + ReLU.  lane holds node m = m0 + quad*4 + r, feat n = nt*16 + col16.
  float bias[4], gg[4], bb[4];
  #pragma unroll
  for (int nt = 0; nt < 4; nt++) {
    int n = nt * 16 + col16;
    bias[nt] = b1[n]; gg[nt] = g1[n]; bb[nt] = be1[n];
  }
  #pragma unroll
  for (int r = 0; r < 4; r++) {
    float v[4];
    #pragma unroll
    for (int nt = 0; nt < 4; nt++) v[nt] = acc[nt][r] + bias[nt];
    float s = (v[0] + v[1]) + (v[2] + v[3]);
    float mu = quad_sum16(s) * (1.f / 64.f);
    float sq = 0.f;
    #pragma unroll
    for (int nt = 0; nt < 4; nt++) { v[nt] -= mu; sq += v[nt] * v[nt]; }
    float var = quad_sum16(sq) * (1.f / 64.f);
    float rstd = rsqrtf(var + LN_EPS);
    int m = m0 + quad * 4 + r;
    if (m < NN) {
      #pragma unroll
      for (int nt = 0; nt < 4; nt++) {
        float o = fmaxf(v[nt] * rstd * gg[nt] + bb[nt], 0.f);
        unsigned short hh = f2bf(o);
        size_t idx = (size_t)m * HG + nt * 16 + col16;
        Ht_hi[idx] = hh;
        Ht_lo[idx] = f2bf(o - bf2f(hh));
      }
    }
  }
}

// ---------------- fused GRU step: M=32/block, gate-aligned tiles, no LDS ----------------
// 4 waves; wave w owns gate cols j in [32w, 32w+32):
//   acc[0,1]=r  acc[2,3]=z  acc[4,5]=Ni  acc[6,7]=Nh ; second index = m-tile (2)
__global__ __launch_bounds__(256, 4) void k_gru_step(
    const unsigned short* __restrict__ Ahi, const unsigned short* __restrict__ Alo,   // Ht planes (NN x 64)
    const unsigned short* __restrict__ Wih_hi, const unsigned short* __restrict__ Wih_lo, // 384 x 64
    const unsigned short* __restrict__ Hhi, const unsigned short* __restrict__ Hlo,   // h planes (NN x 128)
    const unsigned short* __restrict__ Whh_hi, const unsigned short* __restrict__ Whh_lo, // 384 x 128
    const float* __restrict__ bih, const float* __restrict__ bhh,
    float* __restrict__ h, unsigned short* __restrict__ h_hi, unsigned short* __restrict__ h_lo) {
  int tid = threadIdx.x;
  int lane = tid & 63, wave = tid >> 6;
  int col16 = lane & 15, quad = lane >> 4;
  int m0 = blockIdx.x * 32;          // grid 625 * 32 = 20000 exactly
  int gb = 2 * wave;

  f32x4 acc[8][2];
  #pragma unroll
  for (int a = 0; a < 8; a++)
    #pragma unroll
    for (int mt = 0; mt < 2; mt++) acc[a][mt] = (f32x4){0.f, 0.f, 0.f, 0.f};

  // ---- gi: A = Ht (K=64), W = Wih ----
  #pragma unroll
  for (int kk = 0; kk < HG; kk += 32) {
    bf16x8 ah[2], al[2];
    #pragma unroll
    for (int mt = 0; mt < 2; mt++) {
      size_t o = (size_t)(m0 + mt * 16 + col16) * HG + kk + quad * 8;
      ah[mt] = *(const bf16x8*)&Ahi[o];
      al[mt] = *(const bf16x8*)&Alo[o];
    }
    #pragma unroll
    for (int t6 = 0; t6 < 6; t6++) {
      int gt = (t6 < 2) ? (gb + t6) : (t6 < 4) ? (8 + gb + t6 - 2) : (16 + gb + t6 - 4);
      size_t o = (size_t)(gt * 16 + col16) * HG + kk + quad * 8;
      bf16x8 bh = *(const bf16x8*)&Wih_hi[o];
      bf16x8 bl = *(const bf16x8*)&Wih_lo[o];
      #pragma unroll
      for (int mt = 0; mt < 2; mt++) {
        acc[t6][mt] = __builtin_amdgcn_mfma_f32_16x16x32_bf16(ah[mt], bh, acc[t6][mt], 0, 0, 0);
        acc[t6][mt] = __builtin_amdgcn_mfma_f32_16x16x32_bf16(al[mt], bh, acc[t6][mt], 0, 0, 0);
        acc[t6][mt] = __builtin_amdgcn_mfma_f32_16x16x32_bf16(ah[mt], bl, acc[t6][mt], 0, 0, 0);
      }
    }
  }
  // ---- gh: A = h (K=128), W = Whh ----
  #pragma unroll
  for (int kk = 0; kk < HTT; kk += 32) {
    bf16x8 ah[2], al[2];
    #pragma unroll
    for (int mt = 0; mt < 2; mt++) {
      size_t o = (size_t)(m0 + mt * 16 + col16) * HTT + kk + quad * 8;
      ah[mt] = *(const bf16x8*)&Hhi[o];
      al[mt] = *(const bf16x8*)&Hlo[o];
    }
    #pragma unroll
    for (int t6 = 0; t6 < 6; t6++) {
      int gt = (t6 < 2) ? (gb + t6) : (t6 < 4) ? (8 + gb + t6 - 2) : (16 + gb + t6 - 4);
      int ai = (t6 < 4) ? t6 : t6 + 2;        // n-part of gh -> acc[6],acc[7]
      size_t o = (size_t)(gt * 16 + col16) * HTT + kk + quad * 8;
      bf16x8 bh = *(const bf16x8*)&Whh_hi[o];
      bf16x8 bl = *(const bf16x8*)&Whh_lo[o];
      #pragma unroll
      for (int mt = 0; mt < 2; mt++) {
        acc[ai][mt] = __builtin_amdgcn_mfma_f32_16x16x32_bf16(ah[mt], bh, acc[ai][mt], 0, 0, 0);
        acc[ai][mt] = __builtin_amdgcn_mfma_f32_16x16x32_bf16(al[mt], bh, acc[ai][mt], 0, 0, 0);
        acc[ai][mt] = __builtin_amdgcn_mfma_f32_16x16x32_bf16(ah[mt], bl, acc[ai][mt], 0, 0, 0);
      }
    }
  }

  // ---- gates in registers: lane holds (m = m0+mt*16+quad*4+r, j = (gb+js)*16+col16) ----
  int jj[2]; float bR[2], bZ[2], bNi[2], bNh[2];
  #pragma unroll
  for (int js = 0; js < 2; js++) {
    int j = (gb + js) * 16 + col16;
    jj[js] = j;
    bR[js]  = bih[j] + bhh[j];
    bZ[js]  = bih[HTT + j] + bhh[HTT + j];
    bNi[js] = bih[2 * HTT + j];
    bNh[js] = bhh[2 * HTT + j];
  }
  #pragma unroll
  for (int mt = 0; mt < 2; mt++) {
    #pragma unroll
    for (int r = 0; r < 4; r++) {
      int m = m0 + mt * 16 + quad * 4 + r;
      #pragma unroll
      for (int js = 0; js < 2; js++) {
        int j = jj[js];
        float R  = acc[0 + js][mt][r] + bR[js];
        float Z  = acc[2 + js][mt][r] + bZ[js];
        float Ni = acc[4 + js][mt][r] + bNi[js];
        float Nh = acc[6 + js][mt][r] + bNh[js];
        float rg = 1.f / (1.f + __expf(-R));
        float zg = 1.f / (1.f + __expf(-Z));
        float x = Ni + rg * Nh;
        float e = __expf(-2.f * fabsf(x));
        float th = (1.f - e) / (1.f + e);
        float nn = copysignf(th, x);
        size_t idx = (size_t)m * HTT + j;
        float hn = (1.f - zg) * nn + zg * h[idx];
        h[idx] = hn;
        unsigned short hh = f2bf(hn);
        h_hi[idx] = hh;
        h_lo[idx] = f2bf(hn - bf2f(hh));
      }
    }
  }
}

// ---------------- head ----------------
__global__ __launch_bounds__(256) void k_head(
    const float* __restrict__ h, const float* __restrict__ hw,
    const float* __restrict__ hb, float* __restrict__ out) {
  int lane = threadIdx.x & 63;
  int n = blockIdx.x * 4 + (threadIdx.x >> 6);
  if (n >= NN) return;
  float v = h[n * HTT + lane] * hw[lane] + h[n * HTT + 64 + lane] * hw[64 + lane];
  v = wave_sum64(v);
  if (lane == 0) out[n] = v + hb[0];
}

extern "C" void kernel_launch(void* const* d_in, const int* in_sizes, int n_in,
                              void* d_out, int out_size, void* d_ws, size_t ws_size,
                              hipStream_t stream) {
  const float* x_seq = (const float*)d_in[0];
  const int*   edge  = (const int*)d_in[1];
  const float* Wl0   = (const float*)d_in[2];
  const float* Wr0   = (const float*)d_in[3];
  const float* b0    = (const float*)d_in[4];
  const float* g0    = (const float*)d_in[5];
  const float* be0   = (const float*)d_in[6];
  const float* Wl1   = (const float*)d_in[7];
  const float* Wr1   = (const float*)d_in[8];
  const float* b1    = (const float*)d_in[9];
  const float* g1    = (const float*)d_in[10];
  const float* be1   = (const float*)d_in[11];
  const float* Wih   = (const float*)d_in[12];
  const float* Whh   = (const float*)d_in[13];
  const float* bih   = (const float*)d_in[14];
  const float* bhh   = (const float*)d_in[15];
  const float* headW = (const float*)d_in[16];
  const float* headb = (const float*)d_in[17];
  float* out = (float*)d_out;

  const int* srcp = edge;
  const int* dstp = edge + NE;

  char* ws = (char*)d_ws;
  size_t off = 0;
  auto alloc = [&](size_t bytes) -> void* {
    void* p = ws + off;
    off += (bytes + 255) & ~(size_t)255;
    return p;
  };
  int*   cnt     = (int*)alloc(NN * 4);
  int*   row_ptr = (int*)alloc((NN + 1) * 4);
  int*   col     = (int*)alloc(NE * 4);
  float* deg_inv = (float*)alloc(NN * 4);
  float* h0f     = (float*)alloc((size_t)NN * HG * 4);
  unsigned short* h0hi  = (unsigned short*)alloc((size_t)NN * HG * 2);
  unsigned short* h0lo  = (unsigned short*)alloc((size_t)NN * HG * 2);
  unsigned short* agghi = (unsigned short*)alloc((size_t)NN * HG * 2);
  unsigned short* agglo = (unsigned short*)alloc((size_t)NN * HG * 2);
  unsigned short* Ht_hi = (unsigned short*)alloc((size_t)NN * HG * 2);
  unsigned short* Ht_lo = (unsigned short*)alloc((size_t)NN * HG * 2);
  float* h       = (float*)alloc((size_t)NN * HTT * 4);
  unsigned short* h_hi = (unsigned short*)alloc((size_t)NN * HTT * 2);
  unsigned short* h_lo = (unsigned short*)alloc((size_t)NN * HTT * 2);
  unsigned short* Wih_hi = (unsigned short*)alloc((size_t)NG * HG * 2);
  unsigned short* Wih_lo = (unsigned short*)alloc((size_t)NG * HG * 2);
  unsigned short* Whh_hi = (unsigned short*)alloc((size_t)NG * HTT * 2);
  unsigned short* Whh_lo = (unsigned short*)alloc((size_t)NG * HTT * 2);
  unsigned short* Wchi   = (unsigned short*)alloc((size_t)HG * 128 * 2);
  unsigned short* Wclo   = (unsigned short*)alloc((size_t)HG * 128 * 2);
  (void)ws_size; (void)in_sizes; (void)n_in; (void)out_size;

  k_init<<<512, 256, 0, stream>>>(cnt, h, h_hi, h_lo);
  k_hist<<<(NE + 255) / 256, 256, 0, stream>>>(dstp, cnt);
  k_scan<<<1, 1024, 0, stream>>>(cnt, row_ptr, deg_inv);
  k_fill<<<(NE + 255) / 256, 256, 0, stream>>>(srcp, dstp, cnt, col);
  k_cvt<<<(NG * HG + 255) / 256, 256, 0, stream>>>(Wih, Wih_hi, Wih_lo, NG * HG);
  k_cvt<<<(NG * HTT + 255) / 256, 256, 0, stream>>>(Whh, Whh_hi, Whh_lo, NG * HTT);
  k_cvt_sage<<<(HG * 128 + 255) / 256, 256, 0, stream>>>(Wl1, Wr1, Wchi, Wclo);

  for (int t = 0; t < TS; t++) {
    const float* x_t = x_seq + (size_t)t * NN;
    k_sage0<<<5000, 256, 0, stream>>>(x_t, row_ptr, col, deg_inv,
                                      Wl0, Wr0, b0, g0, be0, h0f, h0hi, h0lo);
    k_gather<<<5000, 256, 0, stream>>>(h0f, row_ptr, col, deg_inv, agghi, agglo);
    k_sage_mm<<<(NN + 63) / 64, 256, 0, stream>>>(agghi, agglo, h0hi, h0lo,
                                                  Wchi, Wclo, b1, g1, be1, Ht_hi, Ht_lo);
    k_gru_step<<<NN / 32, 256, 0, stream>>>(Ht_hi, Ht_lo, Wih_hi, Wih_lo,
                                            h_hi, h_lo, Whh_hi, Whh_lo,
                                            bih, bhh, h, h_hi, h_lo);
  }
  k_head<<<5000, 256, 0, stream>>>(h, headW, headb, out);
}